// Round 5
// baseline (698.744 us; speedup 1.0000x reference)
//
#include <hip/hip_runtime.h>

// CircularUpsample2: circular pad(3) + upfirdn2d(up=2, 4x4 FIR, pad=(2,1)) + crop.
// Gather form (validated round 2): for output (Y,X), my=Y>>1, py=Y&1, mx=X>>1, px=X&1:
//   out = x[my-2][mx-2]*k[2+py][2+px] + x[my-2][mx-1]*k[2+py][px]
//       + x[my-1][mx-2]*k[py][2+px]   + x[my-1][mx-1]*k[py][px]     (rows/cols mod 128)
// This round: widen to float4 loads + float4 nontemporal stores, 16 outputs/thread.

#define H 128
#define W 128
#define OW 256

using f32x4 = __attribute__((ext_vector_type(4))) float;

__global__ __launch_bounds__(256) void CircularUpsample2_kernel(
    const float* __restrict__ x, const float* __restrict__ kbuf,
    float* __restrict__ out, int total_threads) {
  // 4x4 FIR weights, uniform address -> scalar regs, hoisted out of the loop
  float kw[16];
#pragma unroll
  for (int i = 0; i < 16; ++i) kw[i] = kbuf[i];

  const int stride = gridDim.x * 256;
  for (int idx = blockIdx.x * 256 + threadIdx.x; idx < total_threads; idx += stride) {
    int s    = idx & 31;        // output col octet: X in [8s, 8s+8)
    int rest = idx >> 5;
    int my   = rest & (H - 1);  // output rows 2my, 2my+1
    int bc   = rest >> 7;

    const float* __restrict__ xp = x + (size_t)bc * (H * W);
    float* __restrict__ op = out + (size_t)bc * (4 * H * W);

    int r0 = (my - 2) & (H - 1);
    int r1 = (my - 1) & (H - 1);
    int ca = (4 * s - 4) & (W - 1);  // multiple of 4 -> 16B-aligned, handles wrap
    int cb = 4 * s;                  // 0..124, no wrap

    f32x4 a0 = *(const f32x4*)(xp + r0 * W + ca);
    f32x4 a1 = *(const f32x4*)(xp + r0 * W + cb);
    f32x4 b0 = *(const f32x4*)(xp + r1 * W + ca);
    f32x4 b1 = *(const f32x4*)(xp + r1 * W + cb);

    // input cols (4s-2 .. 4s+2) for the two tap rows
    float u0[5] = {a0.z, a0.w, a1.x, a1.y, a1.z};
    float u1[5] = {b0.z, b0.w, b1.x, b1.y, b1.z};

    float ev[8], od[8];
#pragma unroll
    for (int j = 0; j < 8; ++j) {   // X = 8s + j
      int mxo = j >> 1, px = j & 1; // mx = 4s + mxo; taps at cols mx-2, mx-1
      float A = u0[mxo], B = u0[mxo + 1], C = u1[mxo], D = u1[mxo + 1];
      ev[j] = A * kw[10 + px] + B * kw[8 + px] + C * kw[2 + px] + D * kw[px];      // py=0
      od[j] = A * kw[14 + px] + B * kw[12 + px] + C * kw[6 + px] + D * kw[4 + px]; // py=1
    }

    float* pe = op + (size_t)(2 * my) * OW + 8 * s;
    float* po = pe + OW;
    f32x4 e0 = {ev[0], ev[1], ev[2], ev[3]}, e1 = {ev[4], ev[5], ev[6], ev[7]};
    f32x4 o0 = {od[0], od[1], od[2], od[3]}, o1 = {od[4], od[5], od[6], od[7]};
    // output is write-once, never re-read: nontemporal to keep L2 for input reuse
    __builtin_nontemporal_store(e0, (f32x4*)pe);
    __builtin_nontemporal_store(e1, (f32x4*)(pe + 4));
    __builtin_nontemporal_store(o0, (f32x4*)po);
    __builtin_nontemporal_store(o1, (f32x4*)(po + 4));
  }
}

extern "C" void kernel_launch(void* const* d_in, const int* in_sizes, int n_in,
                              void* d_out, int out_size, void* d_ws, size_t ws_size,
                              hipStream_t stream) {
  const float* x = (const float*)d_in[0];
  const float* k = (const float*)d_in[1];
  float* out = (float*)d_out;

  int bc_count = in_sizes[0] / (H * W);              // 8*256 = 2048
  int total_threads = bc_count * H * (W / 4);        // one thread per (bc, my, octet)
  int nblocks = 2048;                                 // grid-stride (G11), 16 iters

  CircularUpsample2_kernel<<<nblocks, 256, 0, stream>>>(x, k, out, total_threads);
}

// Round 6
// 603.343 us; speedup vs baseline: 1.1581x; 1.1581x over previous
//
#include <hip/hip_runtime.h>

// CircularUpsample2: circular pad(3) + upfirdn2d(up=2, 4x4 FIR, pad=(2,1)) + crop.
// Gather form (validated round 2): for output (Y,X), my=Y>>1, py=Y&1, mx=X>>1, px=X&1:
//   out = x[my-2][mx-2]*k[2+py][2+px] + x[my-2][mx-1]*k[2+py][px]
//       + x[my-1][mx-2]*k[py][2+px]   + x[my-1][mx-1]*k[py][px]     (rows/cols mod 128)
// Round 6: float4 loads (round 5) + plain float4 stores + exact grid (round 2).
// Round 5's nontemporal stores + grid-stride loop regressed ~90us vs round 2 -> reverted.

#define H 128
#define W 128
#define OW 256

using f32x4 = __attribute__((ext_vector_type(4))) float;

__global__ __launch_bounds__(256) void CircularUpsample2_kernel(
    const float* __restrict__ x, const float* __restrict__ kbuf,
    float* __restrict__ out, int bc_count) {
  int idx = blockIdx.x * 256 + threadIdx.x;
  int s    = idx & 31;        // output col octet: X in [8s, 8s+8)
  int rest = idx >> 5;
  int my   = rest & (H - 1);  // output rows 2my, 2my+1
  int bc   = rest >> 7;
  if (bc >= bc_count) return;

  // 4x4 FIR weights, uniform address -> scalar loads
  float kw[16];
#pragma unroll
  for (int i = 0; i < 16; ++i) kw[i] = kbuf[i];

  const float* __restrict__ xp = x + (size_t)bc * (H * W);
  float* __restrict__ op = out + (size_t)bc * (4 * H * W);

  int r0 = (my - 2) & (H - 1);
  int r1 = (my - 1) & (H - 1);
  int ca = (4 * s - 4) & (W - 1);  // multiple of 4 -> 16B-aligned, handles wrap
  int cb = 4 * s;                  // 0..124, no wrap

  f32x4 a0 = *(const f32x4*)(xp + r0 * W + ca);
  f32x4 a1 = *(const f32x4*)(xp + r0 * W + cb);
  f32x4 b0 = *(const f32x4*)(xp + r1 * W + ca);
  f32x4 b1 = *(const f32x4*)(xp + r1 * W + cb);

  // input cols (4s-2 .. 4s+2) for the two tap rows
  float u0[5] = {a0.z, a0.w, a1.x, a1.y, a1.z};
  float u1[5] = {b0.z, b0.w, b1.x, b1.y, b1.z};

  float ev[8], od[8];
#pragma unroll
  for (int j = 0; j < 8; ++j) {   // X = 8s + j
    int mxo = j >> 1, px = j & 1; // mx = 4s + mxo; taps at cols mx-2, mx-1
    float A = u0[mxo], B = u0[mxo + 1], C = u1[mxo], D = u1[mxo + 1];
    ev[j] = A * kw[10 + px] + B * kw[8 + px] + C * kw[2 + px] + D * kw[px];      // py=0
    od[j] = A * kw[14 + px] + B * kw[12 + px] + C * kw[6 + px] + D * kw[4 + px]; // py=1
  }

  float* pe = op + (size_t)(2 * my) * OW + 8 * s;
  float* po = pe + OW;
  *(f32x4*)pe       = f32x4{ev[0], ev[1], ev[2], ev[3]};
  *(f32x4*)(pe + 4) = f32x4{ev[4], ev[5], ev[6], ev[7]};
  *(f32x4*)po       = f32x4{od[0], od[1], od[2], od[3]};
  *(f32x4*)(po + 4) = f32x4{od[4], od[5], od[6], od[7]};
}

extern "C" void kernel_launch(void* const* d_in, const int* in_sizes, int n_in,
                              void* d_out, int out_size, void* d_ws, size_t ws_size,
                              hipStream_t stream) {
  const float* x = (const float*)d_in[0];
  const float* k = (const float*)d_in[1];
  float* out = (float*)d_out;

  int bc_count = in_sizes[0] / (H * W);              // 8*256 = 2048
  int total_threads = bc_count * H * (W / 4);        // one thread per (bc, my, octet)
  int nblocks = (total_threads + 255) / 256;         // 32768, exact (no tail)

  CircularUpsample2_kernel<<<nblocks, 256, 0, stream>>>(x, k, out, bc_count);
}

// Round 8
// 603.105 us; speedup vs baseline: 1.1586x; 1.0004x over previous
//
#include <hip/hip_runtime.h>

// CircularUpsample2: circular pad(3) + upfirdn2d(up=2, 4x4 FIR, pad=(2,1)) + crop.
// Gather form (validated round 2): for output (Y,X), my=Y>>1, py=Y&1, mx=X>>1, px=X&1:
//   out = x[my-2][mx-2]*k[2+py][2+px] + x[my-2][mx-1]*k[2+py][px]
//       + x[my-1][mx-2]*k[py][2+px]   + x[my-1][mx-1]*k[py][px]     (rows/cols mod 128)
// Round 7: 4x4 outputs/thread. Wave stores = 4 full 1KiB contiguous rows
// (lane t=0..63 writes float4 at col 4t). Loads = 3 rows x 2 float2 (middle
// input row shared by both output row-pairs): 48B read / 64B written.

#define H 128
#define W 128
#define OW 256

using f32x4 = __attribute__((ext_vector_type(4))) float;
using f32x2 = __attribute__((ext_vector_type(2))) float;

__global__ __launch_bounds__(256) void CircularUpsample2_kernel(
    const float* __restrict__ x, const float* __restrict__ kbuf,
    float* __restrict__ out, int bc_count) {
  int idx = blockIdx.x * 256 + threadIdx.x;
  int t  = idx & 63;          // output cols 4t..4t+3 (full wave covers a row)
  int mp = (idx >> 6) & 63;   // output rows 4mp..4mp+3
  int bc = idx >> 12;
  if (bc >= bc_count) return;

  // 4x4 FIR weights, uniform address -> scalar loads
  float kw[16];
#pragma unroll
  for (int i = 0; i < 16; ++i) kw[i] = kbuf[i];

  const float* __restrict__ xp = x + (size_t)bc * (H * W);
  float* __restrict__ op = out + (size_t)bc * (4 * H * W);

  // input rows 2mp-2, 2mp-1, 2mp (mod 128); middle row shared
  int r0 = (2 * mp - 2) & (H - 1);
  int r1 = (2 * mp - 1) & (H - 1);
  int r2 = (2 * mp) & (H - 1);
  // input cols 2t-2, 2t-1 (contiguous even under wrap: 126,127) and 2t, 2t+1
  int clo = (2 * t - 2) & (W - 1);
  int chi = 2 * t;

  float v0[4], v1[4], v2[4];
  {
    f32x2 a = *(const f32x2*)(xp + r0 * W + clo);
    f32x2 b = *(const f32x2*)(xp + r0 * W + chi);
    v0[0] = a.x; v0[1] = a.y; v0[2] = b.x; v0[3] = b.y;
    f32x2 c = *(const f32x2*)(xp + r1 * W + clo);
    f32x2 d = *(const f32x2*)(xp + r1 * W + chi);
    v1[0] = c.x; v1[1] = c.y; v1[2] = d.x; v1[3] = d.y;
    f32x2 e = *(const f32x2*)(xp + r2 * W + clo);
    f32x2 f = *(const f32x2*)(xp + r2 * W + chi);
    v2[0] = e.x; v2[1] = e.y; v2[2] = f.x; v2[3] = f.y;
  }

#pragma unroll
  for (int q = 0; q < 4; ++q) {        // output row 4mp+q
    const float* ra = (q < 2) ? v0 : v1;  // taps from row my-2
    const float* rb = (q < 2) ? v1 : v2;  // taps from row my-1
    int py = q & 1;
    float o[4];
#pragma unroll
    for (int j = 0; j < 4; ++j) {      // output col 4t+j
      int h = j >> 1, px = j & 1;
      o[j] = ra[h]     * kw[(2 + py) * 4 + 2 + px]
           + ra[h + 1] * kw[(2 + py) * 4 + px]
           + rb[h]     * kw[py * 4 + 2 + px]
           + rb[h + 1] * kw[py * 4 + px];
    }
    *(f32x4*)(op + (size_t)(4 * mp + q) * OW + 4 * t) = f32x4{o[0], o[1], o[2], o[3]};
  }
}

extern "C" void kernel_launch(void* const* d_in, const int* in_sizes, int n_in,
                              void* d_out, int out_size, void* d_ws, size_t ws_size,
                              hipStream_t stream) {
  const float* x = (const float*)d_in[0];
  const float* k = (const float*)d_in[1];
  float* out = (float*)d_out;

  int bc_count = in_sizes[0] / (H * W);          // 8*256 = 2048
  int total_threads = bc_count * 64 * 64;        // (bc, row-quad, col-quad)
  int nblocks = (total_threads + 255) / 256;     // 16384, exact

  CircularUpsample2_kernel<<<nblocks, 256, 0, stream>>>(x, k, out, bc_count);
}